// Round 5
// baseline (424.163 us; speedup 1.0000x reference)
//
#include <hip/hip_runtime.h>
#include <math.h>

namespace {
constexpr int Brows = 32768;
constexpr int Dd = 256;
constexpr int Kk = 1024;

// reference python-scalar constants (f64) cast to f32 at use, numpy-style
constexpr double kAlpha64 = 0.01;
constexpr double kC164 = 1.0 - 2.0 * 0.01;            // 0.98
constexpr double kEps64 = 0.01 / (1.0 - 2.0 * 0.01);  // boundary eps
constexpr double kLo64 = -kEps64;
constexpr double kHi64 = 1.0 + kEps64;

// ws float offsets
constexpr int WS_E1W = 0;       // exp(a1w) f32        [256]
constexpr int WS_WD = 256;      // fl(bmax-bmin)       [256]
constexpr int WS_P = 512;       // (1-sc)*exp(a2w)     [256]
constexpr int WS_Q = 768;       // a2b*exp(a2w)        [256]
constexpr int WS_C = 1024;      // scalar constant     [1]
constexpr int WS_AA = 1088;     // ||a_k||^2 f32 numpy-pairwise [1024]
constexpr int WS_LSM = 2112;    // log_softmax(mix)    [1024]
}  // namespace

// ---------------- per-column constants + scalar C ----------------
__global__ void precol_kernel(const float* __restrict__ a1w,
                              const float* __restrict__ a2w,
                              const float* __restrict__ a2b,
                              const float* __restrict__ shiftc,
                              const float* __restrict__ bmin,
                              const float* __restrict__ bmax,
                              float* __restrict__ ws) {
  const int d = threadIdx.x;  // 256 threads
  const float w1 = a1w[d], w2 = a2w[d];
  const float wd = __fsub_rn(bmax[d], bmin[d]);  // fl(bmax-bmin), numpy order
  const float sc = 1.0f / (1.0f + expf(-shiftc[d])) * 0.98f + 0.01f;
  const float e2 = expf(w2);
  ws[WS_E1W + d] = expf(w1);
  ws[WS_WD + d] = wd;
  ws[WS_P + d] = (1.0f - sc) * e2;
  ws[WS_Q + d] = a2b[d] * e2;
  float contrib = -w1 - w2 - logf(wd) - logf(1.0f - sc);
#pragma unroll
  for (int o = 32; o > 0; o >>= 1) contrib += __shfl_xor(contrib, o, 64);
  __shared__ float red[4];
  if ((d & 63) == 0) red[d >> 6] = contrib;
  __syncthreads();
  if (d == 0) {
    float Cv = red[0] + red[1] + red[2] + red[3];
    // -D*log(c1) is the logit logdet constant; rescale adds -(-log(hi-lo)*D)
    Cv += (float)Dd * (float)(log(kC164) + log(kHi64 - kLo64));
    ws[WS_C] = Cv;
  }
}

// numpy pairwise sum of squares, n=256 contiguous f32 (exact replication):
// pairwise(a,256) = block128(a) + block128(a+128); block128 = 8-accumulator
// unroll, combined ((r0+r1)+(r2+r3))+((r4+r5)+(r6+r7)). All ops exact f32.
template <typename F>
__device__ inline float pw128_sq(F ld) {
  float r[8];
#pragma unroll
  for (int j = 0; j < 8; ++j) {
    const float v = ld(j);
    r[j] = __fmul_rn(v, v);
  }
  for (int i = 8; i < 128; i += 8) {
#pragma unroll
    for (int j = 0; j < 8; ++j) {
      const float v = ld(i + j);
      r[j] = __fadd_rn(r[j], __fmul_rn(v, v));
    }
  }
  const float s01 = __fadd_rn(r[0], r[1]);
  const float s23 = __fadd_rn(r[2], r[3]);
  const float s45 = __fadd_rn(r[4], r[5]);
  const float s67 = __fadd_rn(r[6], r[7]);
  return __fadd_rn(__fadd_rn(s01, s23), __fadd_rn(s45, s67));
}

// ---------------- ||a_k||^2 via numpy pairwise (f32) ----------------
__global__ void anorm_kernel(const float* __restrict__ anchors,
                             float* __restrict__ ws) {
  const int k = blockIdx.x * 256 + threadIdx.x;  // 4 blocks x 256
  const float* a = anchors + (size_t)k * Dd;
  const float b0 = pw128_sq([&](int i) { return a[i]; });
  const float b1 = pw128_sq([&](int i) { return a[128 + i]; });
  ws[WS_AA + k] = __fadd_rn(b0, b1);
}

// ---------------- log_softmax(mixture_logits) ----------------
__global__ void lsm_kernel(const float* __restrict__ logits,
                           float* __restrict__ ws) {
  __shared__ float sm[1024];
  const int t = threadIdx.x;  // 1024 threads
  const float v = logits[t];
  sm[t] = v;
  __syncthreads();
  for (int o = 512; o > 0; o >>= 1) {
    if (t < o) sm[t] = fmaxf(sm[t], sm[t + o]);
    __syncthreads();
  }
  const float mx = sm[0];
  __syncthreads();
  sm[t] = expf(v - mx);
  __syncthreads();
  for (int o = 512; o > 0; o >>= 1) {
    if (t < o) sm[t] += sm[t + o];
    __syncthreads();
  }
  const float lse = mx + logf(sm[0]);
  ws[WS_LSM + t] = v - lse;
}

// ---------------- main fused kernel: 64 rows / block ----------------
__global__ __launch_bounds__(256, 2) void voronoi_main(
    const float* __restrict__ x, const float* __restrict__ logp_in,
    const float* __restrict__ a1b, const float* __restrict__ anchors,
    const float* __restrict__ bmin, const float* __restrict__ ws,
    float* __restrict__ out) {
  __shared__ float xt[Dd][68];   // x5 transposed: xt[d][row], 69632 B
  __shared__ float at[32][68];   // anchor tile transposed: at[d][k], 8704 B
  __shared__ float logdet_s[64];
  __shared__ float xx_s[64];
  __shared__ int bidx_s[64];

  const int t = threadIdx.x;
  const int r0 = blockIdx.x * 64;

  const float LOF = (float)kLo64;         // fl32 of python-f64 lo
  const float HLF = (float)(kHi64 - kLo64);  // fl32 of python-f64 (hi-lo)
  const float ALPHAF = (float)kAlpha64;
  const float C1F = (float)kC164;

  // ---- stage 1: literal f32 step-by-step transform -> xt, logdet ----
  {
    const int r = t >> 2, j = t & 3;
    const float* xrow = x + (size_t)(r0 + r) * Dd;
    float ld = 0.0f;
#pragma unroll
    for (int it = 0; it < 16; ++it) {
      const int c = it * 16 + j * 4;
      const float4 xv = *(const float4*)(xrow + c);
      const float4 bv = *(const float4*)(a1b + c);
      const float4 ev = *(const float4*)(ws + WS_E1W + c);
      const float4 wv = *(const float4*)(ws + WS_WD + c);
      const float4 mv = *(const float4*)(bmin + c);
      const float xs[4] = {xv.x, xv.y, xv.z, xv.w};
      const float bs[4] = {bv.x, bv.y, bv.z, bv.w};
      const float es[4] = {ev.x, ev.y, ev.z, ev.w};
      const float wds[4] = {wv.x, wv.y, wv.z, wv.w};
      const float ms[4] = {mv.x, mv.y, mv.z, mv.w};
#pragma unroll
      for (int w = 0; w < 4; ++w) {
        // y = (x + bias) * exp(weight)   [fl(fl(x+b)*e)]
        const float y = __fmul_rn(__fadd_rn(xs[w], bs[w]), es[w]);
        const float ay = fabsf(y);
        const float e = expf(-ay);  // e^{-|y|} in (0,1]
        ld += -ay - 2.0f * log1pf(e);  // logdet: loose tolerance, fast ok
        // stable piecewise sigmoid (scipy expit / jax.nn.sigmoid)
        const float den = __fadd_rn(1.0f, e);
        const float s =
            (y >= 0.0f) ? __fdiv_rn(1.0f, den) : __fdiv_rn(e, den);
        // x3 = (s - alpha) / (1 - 2 alpha)
        const float x3 = __fdiv_rn(__fsub_rn(s, ALPHAF), C1F);
        // x4 = (x3 - lo) / (hi - lo)
        const float x4v = __fdiv_rn(__fsub_rn(x3, LOF), HLF);
        // x5 = x4*(bmax-bmin) + bmin   [separate mul, add — no FMA]
        const float x5 = __fadd_rn(__fmul_rn(x4v, wds[w]), ms[w]);
        xt[c + w][r] = x5;
      }
    }
    ld += __shfl_xor(ld, 1, 64);
    ld += __shfl_xor(ld, 2, 64);
    if (j == 0) logdet_s[r] = ld;
  }
  __syncthreads();

  // ---- row xx = sum(x5*x5) in numpy pairwise order ----
  if (t < 64) {
    const float b0 = pw128_sq([&](int i) { return xt[i][t]; });
    const float b1 = pw128_sq([&](int i) { return xt[128 + i][t]; });
    xx_s[t] = __fadd_rn(b0, b1);
  }
  __syncthreads();

  // ---- stage 2: dot GEMM (sequential-K FMA) + d2 argmin ----
  const int tc = t & 15, tr = t >> 4;
  const int tr4 = tr * 4, tc4 = tc * 4;
  float xxr[4];
#pragma unroll
  for (int i = 0; i < 4; ++i) xxr[i] = xx_s[tr4 + i];
  float bd2[4];
  int bidx[4];
#pragma unroll
  for (int i = 0; i < 4; ++i) {
    bd2[i] = 3.0e38f;
    bidx[i] = 0;
  }

  for (int kt = 0; kt < 16; ++kt) {
    float acc[4][4];
#pragma unroll
    for (int i = 0; i < 4; ++i)
#pragma unroll
      for (int j = 0; j < 4; ++j) acc[i][j] = 0.0f;

    for (int dc = 0; dc < 8; ++dc) {
      __syncthreads();  // protect at[] reads of previous chunk
#pragma unroll
      for (int m = 0; m < 2; ++m) {
        const int f = t + m * 256;
        const int kk = f >> 3, cp = f & 7;
        const float4 av = *(const float4*)(anchors +
                                           (size_t)(kt * 64 + kk) * Dd +
                                           dc * 32 + cp * 4);
        at[cp * 4 + 0][kk] = av.x;
        at[cp * 4 + 1][kk] = av.y;
        at[cp * 4 + 2][kk] = av.z;
        at[cp * 4 + 3][kk] = av.w;
      }
      __syncthreads();
      const int db = dc * 32;
#pragma unroll
      for (int dd = 0; dd < 32; ++dd) {
        const float4 xf = *(const float4*)(&xt[db + dd][tr4]);
        const float4 af = *(const float4*)(&at[dd][tc4]);
        acc[0][0] = fmaf(xf.x, af.x, acc[0][0]);
        acc[0][1] = fmaf(xf.x, af.y, acc[0][1]);
        acc[0][2] = fmaf(xf.x, af.z, acc[0][2]);
        acc[0][3] = fmaf(xf.x, af.w, acc[0][3]);
        acc[1][0] = fmaf(xf.y, af.x, acc[1][0]);
        acc[1][1] = fmaf(xf.y, af.y, acc[1][1]);
        acc[1][2] = fmaf(xf.y, af.z, acc[1][2]);
        acc[1][3] = fmaf(xf.y, af.w, acc[1][3]);
        acc[2][0] = fmaf(xf.z, af.x, acc[2][0]);
        acc[2][1] = fmaf(xf.z, af.y, acc[2][1]);
        acc[2][2] = fmaf(xf.z, af.z, acc[2][2]);
        acc[2][3] = fmaf(xf.z, af.w, acc[2][3]);
        acc[3][0] = fmaf(xf.w, af.x, acc[3][0]);
        acc[3][1] = fmaf(xf.w, af.y, acc[3][1]);
        acc[3][2] = fmaf(xf.w, af.z, acc[3][2]);
        acc[3][3] = fmaf(xf.w, af.w, acc[3][3]);
      }
    }
    // d2[k] = fl(fl(xx - 2*dot) + aa)   [numpy expression order]
#pragma unroll
    for (int j = 0; j < 4; ++j) {
      const int k = kt * 64 + tc4 + j;
      const float aa = ws[WS_AA + k];
#pragma unroll
      for (int i = 0; i < 4; ++i) {
        const float twod = __fadd_rn(acc[i][j], acc[i][j]);  // exact 2*dot
        const float d2 = __fadd_rn(__fsub_rn(xxr[i], twod), aa);
        if (d2 < bd2[i]) {  // strict <, k ascending per lane -> first index
          bd2[i] = d2;
          bidx[i] = k;
        }
      }
    }
  }
  // argmin merge across the 16 tc-lanes sharing the same 4 rows
#pragma unroll
  for (int o = 1; o < 16; o <<= 1) {
#pragma unroll
    for (int i = 0; i < 4; ++i) {
      const float od = __shfl_xor(bd2[i], o, 64);
      const int oi = __shfl_xor(bidx[i], o, 64);
      if (od < bd2[i] || (od == bd2[i] && oi < bidx[i])) {
        bd2[i] = od;
        bidx[i] = oi;
      }
    }
  }
  if (tc == 0) {
#pragma unroll
    for (int i = 0; i < 4; ++i) bidx_s[tr4 + i] = bidx[i];
  }
  __syncthreads();

  // ---- epilogue: out_x = (x5 - a_k)*p + q ; logp ; idx ----
  {
    const int r = t >> 2, j = t & 3;
    const int k = bidx_s[r];
    const float* arow = anchors + (size_t)k * Dd;
    float* orow = out + (size_t)(r0 + r) * Dd;
#pragma unroll
    for (int it = 0; it < 16; ++it) {
      const int c = it * 16 + j * 4;
      const float4 av = *(const float4*)(arow + c);
      const float4 pv = *(const float4*)(ws + WS_P + c);
      const float4 qv = *(const float4*)(ws + WS_Q + c);
      float4 ov;
      ov.x = fmaf(xt[c + 0][r] - av.x, pv.x, qv.x);
      ov.y = fmaf(xt[c + 1][r] - av.y, pv.y, qv.y);
      ov.z = fmaf(xt[c + 2][r] - av.z, pv.z, qv.z);
      ov.w = fmaf(xt[c + 3][r] - av.w, pv.w, qv.w);
      *(float4*)(orow + c) = ov;
    }
  }
  if (t < 64) {
    const int rr = t;
    const int kk2 = bidx_s[rr];
    const float lp =
        logp_in[r0 + rr] + ws[WS_C] - logdet_s[rr] - ws[WS_LSM + kk2];
    out[(size_t)Brows * Dd + r0 + rr] = lp;
    out[(size_t)Brows * Dd + Brows + r0 + rr] = (float)kk2;
  }
}

extern "C" void kernel_launch(void* const* d_in, const int* in_sizes, int n_in,
                              void* d_out, int out_size, void* d_ws,
                              size_t ws_size, hipStream_t stream) {
  const float* x = (const float*)d_in[0];
  const float* logp = (const float*)d_in[1];
  const float* a1b = (const float*)d_in[2];
  const float* a1w = (const float*)d_in[3];
  const float* a2b = (const float*)d_in[4];
  const float* a2w = (const float*)d_in[5];
  const float* shiftc = (const float*)d_in[6];
  const float* anch = (const float*)d_in[7];
  const float* mixl = (const float*)d_in[8];
  const float* bmin = (const float*)d_in[9];
  const float* bmax = (const float*)d_in[10];
  float* ws = (float*)d_ws;
  float* out = (float*)d_out;

  precol_kernel<<<1, 256, 0, stream>>>(a1w, a2w, a2b, shiftc, bmin, bmax, ws);
  anorm_kernel<<<Kk / 256, 256, 0, stream>>>(anch, ws);
  lsm_kernel<<<1, 1024, 0, stream>>>(mixl, ws);
  voronoi_main<<<Brows / 64, 256, 0, stream>>>(x, logp, a1b, anch, bmin, ws,
                                               out);
}

// Round 8
// 379.921 us; speedup vs baseline: 1.1165x; 1.1165x over previous
//
#include <hip/hip_runtime.h>
#include <math.h>

namespace {
constexpr int Brows = 32768;
constexpr int Dd = 256;
constexpr int Kk = 1024;

// reference python-scalar constants (f64) cast to f32 at use, numpy-style
constexpr double kAlpha64 = 0.01;
constexpr double kC164 = 1.0 - 2.0 * 0.01;            // 0.98
constexpr double kEps64 = 0.01 / (1.0 - 2.0 * 0.01);  // boundary eps
constexpr double kLo64 = -kEps64;
constexpr double kHi64 = 1.0 + kEps64;

// ws float offsets
constexpr int WS_E1W = 0;       // exp(a1w) f32        [256]
constexpr int WS_WD = 256;      // fl(bmax-bmin)       [256]
constexpr int WS_P = 512;       // (1-sc)*exp(a2w)     [256]
constexpr int WS_Q = 768;       // a2b*exp(a2w)        [256]
constexpr int WS_C = 1024;      // scalar constant     [1]
constexpr int WS_AA = 1088;     // ||a_k||^2 f32 numpy-pairwise [1024]
constexpr int WS_LSM = 2112;    // log_softmax(mix)    [1024]
}  // namespace

// ---------------- per-column constants + scalar C ----------------
__global__ void precol_kernel(const float* __restrict__ a1w,
                              const float* __restrict__ a2w,
                              const float* __restrict__ a2b,
                              const float* __restrict__ shiftc,
                              const float* __restrict__ bmin,
                              const float* __restrict__ bmax,
                              float* __restrict__ ws) {
  const int d = threadIdx.x;  // 256 threads
  const float w1 = a1w[d], w2 = a2w[d];
  const float wd = __fsub_rn(bmax[d], bmin[d]);  // fl(bmax-bmin), numpy order
  const float sc = 1.0f / (1.0f + expf(-shiftc[d])) * 0.98f + 0.01f;
  const float e2 = expf(w2);
  ws[WS_E1W + d] = expf(w1);
  ws[WS_WD + d] = wd;
  ws[WS_P + d] = (1.0f - sc) * e2;
  ws[WS_Q + d] = a2b[d] * e2;
  float contrib = -w1 - w2 - logf(wd) - logf(1.0f - sc);
#pragma unroll
  for (int o = 32; o > 0; o >>= 1) contrib += __shfl_xor(contrib, o, 64);
  __shared__ float red[4];
  if ((d & 63) == 0) red[d >> 6] = contrib;
  __syncthreads();
  if (d == 0) {
    float Cv = red[0] + red[1] + red[2] + red[3];
    Cv += (float)Dd * (float)(log(kC164) + log(kHi64 - kLo64));
    ws[WS_C] = Cv;
  }
}

// numpy pairwise sum of squares, n=256 contiguous f32 (exact replication):
// pairwise(a,256) = block128(a) + block128(a+128); block128 = 8-accumulator
// unroll, combined ((r0+r1)+(r2+r3))+((r4+r5)+(r6+r7)). All ops exact f32.
template <typename F>
__device__ inline float pw128_sq(F ld) {
  float r[8];
#pragma unroll
  for (int j = 0; j < 8; ++j) {
    const float v = ld(j);
    r[j] = __fmul_rn(v, v);
  }
  for (int i = 8; i < 128; i += 8) {
#pragma unroll
    for (int j = 0; j < 8; ++j) {
      const float v = ld(i + j);
      r[j] = __fadd_rn(r[j], __fmul_rn(v, v));
    }
  }
  const float s01 = __fadd_rn(r[0], r[1]);
  const float s23 = __fadd_rn(r[2], r[3]);
  const float s45 = __fadd_rn(r[4], r[5]);
  const float s67 = __fadd_rn(r[6], r[7]);
  return __fadd_rn(__fadd_rn(s01, s23), __fadd_rn(s45, s67));
}

// ---------------- ||a_k||^2 via numpy pairwise (f32) ----------------
__global__ void anorm_kernel(const float* __restrict__ anchors,
                             float* __restrict__ ws) {
  const int k = blockIdx.x * 256 + threadIdx.x;  // 4 blocks x 256
  const float* a = anchors + (size_t)k * Dd;
  const float b0 = pw128_sq([&](int i) { return a[i]; });
  const float b1 = pw128_sq([&](int i) { return a[128 + i]; });
  ws[WS_AA + k] = __fadd_rn(b0, b1);
}

// ---------------- log_softmax(mixture_logits) ----------------
__global__ void lsm_kernel(const float* __restrict__ logits,
                           float* __restrict__ ws) {
  __shared__ float sm[1024];
  const int t = threadIdx.x;  // 1024 threads
  const float v = logits[t];
  sm[t] = v;
  __syncthreads();
  for (int o = 512; o > 0; o >>= 1) {
    if (t < o) sm[t] = fmaxf(sm[t], sm[t + o]);
    __syncthreads();
  }
  const float mx = sm[0];
  __syncthreads();
  sm[t] = expf(v - mx);
  __syncthreads();
  for (int o = 512; o > 0; o >>= 1) {
    if (t < o) sm[t] += sm[t + o];
    __syncthreads();
  }
  const float lse = mx + logf(sm[0]);
  ws[WS_LSM + t] = v - lse;
}

// ---------------- main fused kernel: 64 rows / block ----------------
// Stage-2 tiling: wave w owns rows w*16..w*16+15 (xf reads are wave-broadcast);
// lane tc=t&63 owns anchors tc*4..tc*4+3 of each 256-anchor kt tile (af reads
// are fully-contiguous 1KiB/wave). Both patterns are LDS-conflict-free.
__global__ __launch_bounds__(256, 2) void voronoi_main(
    const float* __restrict__ x, const float* __restrict__ logp_in,
    const float* __restrict__ a1b, const float* __restrict__ anchors,
    const float* __restrict__ bmin, const float* __restrict__ ws,
    float* __restrict__ out) {
  __shared__ float xt[Dd][68];  // x5 transposed: xt[d][row], 69632 B
  __shared__ float at[8][256];  // anchor dim-chunk: at[d][k], 8192 B
  __shared__ float logdet_s[64];
  __shared__ float xx_s[64];
  __shared__ int bidx_s[64];

  const int t = threadIdx.x;
  const int r0 = blockIdx.x * 64;

  const float LOF = (float)kLo64;            // fl32 of python-f64 lo
  const float HLF = (float)(kHi64 - kLo64);  // fl32 of python-f64 (hi-lo)
  const float ALPHAF = (float)kAlpha64;
  const float C1F = (float)kC164;

  // ---- stage 1: literal f32 step-by-step transform -> xt, logdet ----
  {
    const int r = t >> 2, j = t & 3;
    const float* xrow = x + (size_t)(r0 + r) * Dd;
    float ld = 0.0f;
#pragma unroll
    for (int it = 0; it < 16; ++it) {
      const int c = it * 16 + j * 4;
      const float4 xv = *(const float4*)(xrow + c);
      const float4 bv = *(const float4*)(a1b + c);
      const float4 ev = *(const float4*)(ws + WS_E1W + c);
      const float4 wv = *(const float4*)(ws + WS_WD + c);
      const float4 mv = *(const float4*)(bmin + c);
      const float xs[4] = {xv.x, xv.y, xv.z, xv.w};
      const float bs[4] = {bv.x, bv.y, bv.z, bv.w};
      const float es[4] = {ev.x, ev.y, ev.z, ev.w};
      const float wds[4] = {wv.x, wv.y, wv.z, wv.w};
      const float ms[4] = {mv.x, mv.y, mv.z, mv.w};
#pragma unroll
      for (int w = 0; w < 4; ++w) {
        // y = (x + bias) * exp(weight)   [fl(fl(x+b)*e)]
        const float y = __fmul_rn(__fadd_rn(xs[w], bs[w]), es[w]);
        const float ay = fabsf(y);
        const float e = expf(-ay);     // e^{-|y|} in (0,1]
        ld += -ay - 2.0f * log1pf(e);  // logdet: loose tolerance, fast ok
        // stable piecewise sigmoid (scipy expit / jax.nn.sigmoid)
        const float den = __fadd_rn(1.0f, e);
        const float s = (y >= 0.0f) ? __fdiv_rn(1.0f, den) : __fdiv_rn(e, den);
        // x3 = (s - alpha) / (1 - 2 alpha)
        const float x3 = __fdiv_rn(__fsub_rn(s, ALPHAF), C1F);
        // x4 = (x3 - lo) / (hi - lo)
        const float x4v = __fdiv_rn(__fsub_rn(x3, LOF), HLF);
        // x5 = x4*(bmax-bmin) + bmin   [separate mul, add — no FMA]
        const float x5 = __fadd_rn(__fmul_rn(x4v, wds[w]), ms[w]);
        xt[c + w][r] = x5;
      }
    }
    ld += __shfl_xor(ld, 1, 64);
    ld += __shfl_xor(ld, 2, 64);
    if (j == 0) logdet_s[r] = ld;
  }
  __syncthreads();

  // ---- row xx = sum(x5*x5) in numpy pairwise order ----
  if (t < 64) {
    const float b0 = pw128_sq([&](int i) { return xt[i][t]; });
    const float b1 = pw128_sq([&](int i) { return xt[128 + i][t]; });
    xx_s[t] = __fadd_rn(b0, b1);
  }
  __syncthreads();

  // ---- stage 2: dot GEMM (TM=16 x TN=4, sequential-K FMA) + d2 argmin ----
  const int tc = t & 63;  // anchor-quad lane 0..63
  const int tr = t >> 6;  // wave id 0..3 -> row group
  const int tr16 = tr * 16, tc4 = tc * 4;

  float xxr[16];
#pragma unroll
  for (int i = 0; i < 16; ++i) xxr[i] = xx_s[tr16 + i];

  float bd2[16];
  int bidx[16];
#pragma unroll
  for (int i = 0; i < 16; ++i) {
    bd2[i] = 3.0e38f;
    bidx[i] = 0;
  }

  for (int kt = 0; kt < 4; ++kt) {  // 256-anchor tiles
    float acc[16][4];
#pragma unroll
    for (int i = 0; i < 16; ++i)
#pragma unroll
      for (int j = 0; j < 4; ++j) acc[i][j] = 0.0f;

    for (int dc = 0; dc < 32; ++dc) {  // 8-dim chunks
      __syncthreads();  // protect at[] reads of previous chunk
#pragma unroll
      for (int m = 0; m < 2; ++m) {
        const int u = t + m * 256;
        const int k = u >> 1, q = u & 1;
        const float4 av = *(const float4*)(anchors +
                                           (size_t)(kt * 256 + k) * Dd +
                                           dc * 8 + q * 4);
        at[q * 4 + 0][k] = av.x;
        at[q * 4 + 1][k] = av.y;
        at[q * 4 + 2][k] = av.z;
        at[q * 4 + 3][k] = av.w;
      }
      __syncthreads();
#pragma unroll
      for (int dd = 0; dd < 8; ++dd) {
        const int dg = dc * 8 + dd;
        const float4 xf0 = *(const float4*)(&xt[dg][tr16]);      // broadcast
        const float4 xf1 = *(const float4*)(&xt[dg][tr16 + 4]);  // broadcast
        const float4 xf2 = *(const float4*)(&xt[dg][tr16 + 8]);  // broadcast
        const float4 xf3 = *(const float4*)(&xt[dg][tr16 + 12]); // broadcast
        const float4 af = *(const float4*)(&at[dd][tc4]);        // contiguous
        const float xv[16] = {xf0.x, xf0.y, xf0.z, xf0.w, xf1.x, xf1.y,
                              xf1.z, xf1.w, xf2.x, xf2.y, xf2.z, xf2.w,
                              xf3.x, xf3.y, xf3.z, xf3.w};
#pragma unroll
        for (int i = 0; i < 16; ++i) {
          acc[i][0] = fmaf(xv[i], af.x, acc[i][0]);
          acc[i][1] = fmaf(xv[i], af.y, acc[i][1]);
          acc[i][2] = fmaf(xv[i], af.z, acc[i][2]);
          acc[i][3] = fmaf(xv[i], af.w, acc[i][3]);
        }
      }
    }
    // d2[k] = fl(fl(xx - 2*dot) + aa)   [numpy expression order]
#pragma unroll
    for (int j = 0; j < 4; ++j) {
      const int k = kt * 256 + tc4 + j;
      const float aa = ws[WS_AA + k];
#pragma unroll
      for (int i = 0; i < 16; ++i) {
        const float twod = __fadd_rn(acc[i][j], acc[i][j]);  // exact 2*dot
        const float d2 = __fadd_rn(__fsub_rn(xxr[i], twod), aa);
        if (d2 < bd2[i]) {  // strict <, k ascending per lane -> first index
          bd2[i] = d2;
          bidx[i] = k;
        }
      }
    }
  }
  // argmin merge across all 64 lanes of the wave (lanes = anchor subsets,
  // lane order = ascending k -> first-index tie-break via oi < bidx)
#pragma unroll
  for (int o = 1; o < 64; o <<= 1) {
#pragma unroll
    for (int i = 0; i < 16; ++i) {
      const float od = __shfl_xor(bd2[i], o, 64);
      const int oi = __shfl_xor(bidx[i], o, 64);
      if (od < bd2[i] || (od == bd2[i] && oi < bidx[i])) {
        bd2[i] = od;
        bidx[i] = oi;
      }
    }
  }
  if (tc == 0) {
#pragma unroll
    for (int i = 0; i < 16; ++i) bidx_s[tr16 + i] = bidx[i];
  }
  __syncthreads();

  // ---- epilogue: out_x = (x5 - a_k)*p + q ; logp ; idx ----
  {
    const int r = t >> 2, j = t & 3;
    const int k = bidx_s[r];
    const float* arow = anchors + (size_t)k * Dd;
    float* orow = out + (size_t)(r0 + r) * Dd;
#pragma unroll
    for (int it = 0; it < 16; ++it) {
      const int c = it * 16 + j * 4;
      const float4 av = *(const float4*)(arow + c);
      const float4 pv = *(const float4*)(ws + WS_P + c);
      const float4 qv = *(const float4*)(ws + WS_Q + c);
      float4 ov;
      ov.x = fmaf(xt[c + 0][r] - av.x, pv.x, qv.x);
      ov.y = fmaf(xt[c + 1][r] - av.y, pv.y, qv.y);
      ov.z = fmaf(xt[c + 2][r] - av.z, pv.z, qv.z);
      ov.w = fmaf(xt[c + 3][r] - av.w, pv.w, qv.w);
      *(float4*)(orow + c) = ov;
    }
  }
  if (t < 64) {
    const int rr = t;
    const int kk2 = bidx_s[rr];
    const float lp =
        logp_in[r0 + rr] + ws[WS_C] - logdet_s[rr] - ws[WS_LSM + kk2];
    out[(size_t)Brows * Dd + r0 + rr] = lp;
    out[(size_t)Brows * Dd + Brows + r0 + rr] = (float)kk2;
  }
}

extern "C" void kernel_launch(void* const* d_in, const int* in_sizes, int n_in,
                              void* d_out, int out_size, void* d_ws,
                              size_t ws_size, hipStream_t stream) {
  const float* x = (const float*)d_in[0];
  const float* logp = (const float*)d_in[1];
  const float* a1b = (const float*)d_in[2];
  const float* a1w = (const float*)d_in[3];
  const float* a2b = (const float*)d_in[4];
  const float* a2w = (const float*)d_in[5];
  const float* shiftc = (const float*)d_in[6];
  const float* anch = (const float*)d_in[7];
  const float* mixl = (const float*)d_in[8];
  const float* bmin = (const float*)d_in[9];
  const float* bmax = (const float*)d_in[10];
  float* ws = (float*)d_ws;
  float* out = (float*)d_out;

  precol_kernel<<<1, 256, 0, stream>>>(a1w, a2w, a2b, shiftc, bmin, bmax, ws);
  anorm_kernel<<<Kk / 256, 256, 0, stream>>>(anch, ws);
  lsm_kernel<<<1, 1024, 0, stream>>>(mixl, ws);
  voronoi_main<<<Brows / 64, 256, 0, stream>>>(x, logp, a1b, anch, bmin, ws,
                                               out);
}